// Round 8
// baseline (1905.612 us; speedup 1.0000x reference)
//
#include <hip/hip_runtime.h>
#include <hip/hip_bf16.h>

typedef __attribute__((ext_vector_type(4))) float f32x4;

// ---------------- degree count ----------------
__global__ void count_kernel(const int* __restrict__ dst, int* __restrict__ cnt, int E) {
    int i = blockIdx.x * blockDim.x + threadIdx.x;
    if (i < E) atomicAdd(&cnt[dst[i]], 1);
}

// ---------------- scan1: block-local exclusive scan + dis = 1/sqrt(deg+1) ----------
__global__ void scan1_kernel(const int* __restrict__ cnt, int* __restrict__ offs,
                             int* __restrict__ bsums, float* __restrict__ dis, int n) {
    const int t = threadIdx.x, lane = t & 63, w = t >> 6;
    const int base = blockIdx.x * 1024 + t * 4;
    int v0 = (base + 0 < n) ? cnt[base + 0] : 0;
    int v1 = (base + 1 < n) ? cnt[base + 1] : 0;
    int v2 = (base + 2 < n) ? cnt[base + 2] : 0;
    int v3 = (base + 3 < n) ? cnt[base + 3] : 0;
    if (base + 0 < n) dis[base + 0] = (float)(1.0 / sqrt((double)(v0 + 1)));
    if (base + 1 < n) dis[base + 1] = (float)(1.0 / sqrt((double)(v1 + 1)));
    if (base + 2 < n) dis[base + 2] = (float)(1.0 / sqrt((double)(v2 + 1)));
    if (base + 3 < n) dis[base + 3] = (float)(1.0 / sqrt((double)(v3 + 1)));
    int s = v0 + v1 + v2 + v3;
    int incl = s;
    #pragma unroll
    for (int off = 1; off < 64; off <<= 1) {
        int y = __shfl_up(incl, off);
        if (lane >= off) incl += y;
    }
    __shared__ int wsum[4];
    if (lane == 63) wsum[w] = incl;
    __syncthreads();
    int wbase = 0;
    #pragma unroll
    for (int k = 0; k < 4; ++k) if (k < w) wbase += wsum[k];
    int run = wbase + incl - s;
    if (base + 0 < n) offs[base + 0] = run; run += v0;
    if (base + 1 < n) offs[base + 1] = run; run += v1;
    if (base + 2 < n) offs[base + 2] = run; run += v2;
    if (base + 3 < n) offs[base + 3] = run;
    if (t == 255) bsums[blockIdx.x] = wbase + incl;
}

__global__ void scan2_kernel(int* __restrict__ bsums, int nb) {
    const int t = threadIdx.x, lane = t & 63, w = t >> 6;  // 128 threads
    int s = (t < nb) ? bsums[t] : 0;
    int incl = s;
    #pragma unroll
    for (int off = 1; off < 64; off <<= 1) {
        int y = __shfl_up(incl, off);
        if (lane >= off) incl += y;
    }
    __shared__ int wsum[2];
    if (lane == 63) wsum[w] = incl;
    __syncthreads();
    int wbase = (w == 1) ? wsum[0] : 0;
    if (t < nb) bsums[t] = wbase + incl - s;
}

// scan3: finalize offsets; emit cursor and packed (start,cnt) meta
__global__ void scan3_kernel(const int* __restrict__ offs, const int* __restrict__ bsums,
                             const int* __restrict__ cnt, int* __restrict__ cursor,
                             int2* __restrict__ meta, int n) {
    int i = blockIdx.x * blockDim.x + threadIdx.x;
    if (i < n) {
        int v = offs[i] + bsums[i >> 10];
        cursor[i] = v;
        meta[i] = make_int2(v, cnt[i]);
    }
}

// ---------------- CSR fill ----------------
__global__ void fill_kernel(const int* __restrict__ src, const int* __restrict__ dst,
                            const float* __restrict__ dis, int* __restrict__ cursor,
                            int* __restrict__ csr_src, float* __restrict__ csr_norm, int E) {
    int i = blockIdx.x * blockDim.x + threadIdx.x;
    if (i < E) {
        int s = src[i], d = dst[i];
        int pos = atomicAdd(&cursor[d], 1);
        csr_src[pos] = s;
        csr_norm[pos] = dis[s] * dis[d];
    }
}

// =============== Layer 1: [N,2] -> [N,16]. Wave per node, W hoisted (3 regs). =====
__global__ __launch_bounds__(256, 4)
void gcn_l1(const float* __restrict__ x, const int2* __restrict__ meta,
            const int* __restrict__ csr_src, const float* __restrict__ csr_norm,
            const float* __restrict__ dis, const float* __restrict__ W,
            const float* __restrict__ B, float* __restrict__ h1, int n, int nwaves) {
    const int lane = threadIdx.x & 63;
    const int wid = blockIdx.x * (blockDim.x >> 6) + (threadIdx.x >> 6);
    const int chunk = (n + nwaves - 1) / nwaves;
    const int n0 = wid * chunk, n1 = min(n0 + chunk, n);
    const int o = lane & 15;
    const float w0 = W[o], w1 = W[16 + o], bo = B[o];
    for (int node = n0; node < n1; ++node) {
        const int2 mt = meta[node];
        const int start = mt.x, m = mt.y;
        float a0 = 0.f, a1 = 0.f;
        for (int j = lane; j < m; j += 64) {
            const int s2 = csr_src[start + j];
            const float nm = csr_norm[start + j];
            const float2 hv = *(const float2*)(x + 2 * (size_t)s2);
            a0 = fmaf(nm, hv.x, a0);
            a1 = fmaf(nm, hv.y, a1);
        }
        #pragma unroll
        for (int off = 32; off >= 1; off >>= 1) {
            a0 += __shfl_xor(a0, off);
            a1 += __shfl_xor(a1, off);
        }
        const float d0 = dis[node], nms = d0 * d0;
        const float2 hs = *(const float2*)(x + 2 * (size_t)node);
        a0 = fmaf(nms, hs.x, a0);
        a1 = fmaf(nms, hs.y, a1);
        if (lane < 16) {
            const float v = fmaf(a0, w0, fmaf(a1, w1, bo));
            h1[(size_t)node * 16 + o] = fmaxf(v, 0.f);
        }
    }
}

// =============== Quad layer: one WAVE computes 4 nodes. ===========================
// Gather per node (R5-proven asm cluster, 32 slots in flight), agg -> wave-private
// LDS (lgkmcnt sync only, NO barriers). MLP phase node-blocked: each W element
// loaded once per 4 nodes (4x fewer W-load instrs -> un-bottlenecks the TA/L1 pipe).
// FPOOL: contiguous quad -> run-merged atomicMax into pooled (relu>=0, exact).
template <int C_IN, int C_OUT, bool FPOOL>
__global__ __launch_bounds__(256, 4)
void gcn_quad(const float* __restrict__ h_in, const int2* __restrict__ meta,
              const int* __restrict__ csr_src, const float* __restrict__ csr_norm,
              const float* __restrict__ dis, const float* __restrict__ W,
              const float* __restrict__ Bias, float* __restrict__ h_out,
              const int* __restrict__ batchv, float* __restrict__ pooled, int n) {
    constexpr int LPR = C_IN / 4;                      // lanes per row: 4,8,16
    constexpr int EPW = 64 / LPR;                      // edge slots: 16,8,4
    constexpr int LOGL = (LPR == 4) ? 2 : (LPR == 8) ? 3 : 4;
    constexpr int UNROLL = 32 / EPW;                   // 32 slots in flight
    constexpr int HALVES = (C_OUT > 64) ? 2 : 1;
    constexpr int KQ = C_IN / 4;

    __shared__ float sAgg[4][4][C_IN];                 // [wave][node][ch]

    const int wave = threadIdx.x >> 6;
    const int lane = threadIdx.x & 63;
    const int base = (blockIdx.x * 4 + wave) * 4;      // quad's first node

    const int cb = (lane & (LPR - 1)) * 4;             // channel base
    const int sub = lane >> LOGL;                      // edge slot

    int bg[4];

    #pragma unroll
    for (int nd = 0; nd < 4; ++nd) {
        const int node = base + nd;
        const bool valid = node < n;
        const int2 mt = valid ? meta[node] : make_int2(0, 0);
        const int start = mt.x, m = mt.y;
        if (FPOOL) bg[nd] = valid ? batchv[node] : -1;
        float ax = 0.f, ay = 0.f, az = 0.f, aw = 0.f;
        for (int j = sub; j < m; j += UNROLL * EPW) {
            int ss[UNROLL]; float nn[UNROLL];
            #pragma unroll
            for (int u = 0; u < UNROLL; ++u) {
                const int jj = j + u * EPW;
                const bool ok = jj < m;
                const int e = start + (ok ? jj : 0);   // dummy slots: edge 0 (hot), nm=0
                ss[u] = csr_src[e];
                nn[u] = ok ? csr_norm[e] : 0.f;
            }
            f32x4 hv[UNROLL];
            const float* ap[UNROLL];
            #pragma unroll
            for (int u = 0; u < UNROLL; ++u) ap[u] = h_in + (size_t)ss[u] * C_IN + cb;
            #pragma unroll
            for (int u = 0; u < UNROLL; ++u)
                asm volatile("global_load_dwordx4 %0, %1, off"
                             : "=v"(hv[u]) : "v"(ap[u]) : "memory");
            asm volatile("s_waitcnt vmcnt(0)" ::: "memory");
            __builtin_amdgcn_sched_barrier(0);         // rule #18
            #pragma unroll
            for (int u = 0; u < UNROLL; ++u) {
                ax = fmaf(nn[u], hv[u].x, ax); ay = fmaf(nn[u], hv[u].y, ay);
                az = fmaf(nn[u], hv[u].z, az); aw = fmaf(nn[u], hv[u].w, aw);
            }
        }
        #pragma unroll
        for (int off = 32; off >= LPR; off >>= 1) {
            ax += __shfl_xor(ax, off); ay += __shfl_xor(ay, off);
            az += __shfl_xor(az, off); aw += __shfl_xor(aw, off);
        }
        if (valid && lane < LPR) {
            const float d0 = dis[node], nms = d0 * d0;
            const f32x4 hs = *(const f32x4*)(h_in + (size_t)node * C_IN + cb);
            ax = fmaf(nms, hs.x, ax); ay = fmaf(nms, hs.y, ay);
            az = fmaf(nms, hs.z, az); aw = fmaf(nms, hs.w, aw);
            f32x4 t; t.x = ax; t.y = ay; t.z = az; t.w = aw;
            *(f32x4*)&sAgg[wave][nd][cb] = t;
        }
    }
    asm volatile("s_waitcnt lgkmcnt(0)" ::: "memory"); // wave-private LDS: no barrier
    __builtin_amdgcn_sched_barrier(0);                 // rule #18: pin reads below wait

    // ---- node-blocked MLP: each W element serves 4 nodes ----
    int oh[HALVES];
    float v[4][HALVES];
    #pragma unroll
    for (int h = 0; h < HALVES; ++h) {
        oh[h] = (C_OUT >= 64) ? (lane + 64 * h) : (lane & (C_OUT - 1));
        const float b = Bias[oh[h]];
        #pragma unroll
        for (int nd = 0; nd < 4; ++nd) v[nd][h] = b;
    }
    #pragma unroll
    for (int kq = 0; kq < KQ; ++kq) {
        f32x4 a[4];
        #pragma unroll
        for (int nd = 0; nd < 4; ++nd)
            a[nd] = *(const f32x4*)&sAgg[wave][nd][kq * 4];  // broadcast ds_read_b128
        #pragma unroll
        for (int h = 0; h < HALVES; ++h) {
            const float w0 = W[(kq * 4 + 0) * C_OUT + oh[h]];
            const float w1 = W[(kq * 4 + 1) * C_OUT + oh[h]];
            const float w2 = W[(kq * 4 + 2) * C_OUT + oh[h]];
            const float w3 = W[(kq * 4 + 3) * C_OUT + oh[h]];
            #pragma unroll
            for (int nd = 0; nd < 4; ++nd) {
                v[nd][h] = fmaf(a[nd].x, w0, v[nd][h]);
                v[nd][h] = fmaf(a[nd].y, w1, v[nd][h]);
                v[nd][h] = fmaf(a[nd].z, w2, v[nd][h]);
                v[nd][h] = fmaf(a[nd].w, w3, v[nd][h]);
            }
        }
    }

    if constexpr (FPOOL) {
        int curg = -1;
        float run0 = 0.f, run1 = 0.f;
        #pragma unroll
        for (int nd = 0; nd < 4; ++nd) {
            if (bg[nd] >= 0) {
                const float r0 = fmaxf(v[nd][0], 0.f);
                const float r1 = (HALVES > 1) ? fmaxf(v[nd][HALVES - 1], 0.f) : 0.f;
                if (bg[nd] != curg) {
                    if (curg >= 0) {
                        atomicMax((int*)&pooled[(size_t)curg * C_OUT + oh[0]], __float_as_int(run0));
                        if (HALVES > 1)
                            atomicMax((int*)&pooled[(size_t)curg * C_OUT + oh[HALVES - 1]], __float_as_int(run1));
                    }
                    curg = bg[nd]; run0 = r0; run1 = r1;
                } else {
                    run0 = fmaxf(run0, r0);
                    run1 = fmaxf(run1, r1);
                }
            }
        }
        if (curg >= 0) {
            atomicMax((int*)&pooled[(size_t)curg * C_OUT + oh[0]], __float_as_int(run0));
            if (HALVES > 1)
                atomicMax((int*)&pooled[(size_t)curg * C_OUT + oh[HALVES - 1]], __float_as_int(run1));
        }
    } else {
        #pragma unroll
        for (int nd = 0; nd < 4; ++nd) {
            const int node = base + nd;
            if (node < n) {
                #pragma unroll
                for (int h = 0; h < HALVES; ++h) {
                    if (C_OUT >= 64 || lane < C_OUT)
                        h_out[(size_t)node * C_OUT + oh[h]] = fmaxf(v[nd][h], 0.f);
                }
            }
        }
    }
}

// ---------------- MLP head: relu(pooled @ W5 + b5) @ W6 + b6 ----------------
__global__ void mlp_kernel(const float* __restrict__ pooled,
                           const float* __restrict__ W5, const float* __restrict__ b5,
                           const float* __restrict__ W6, const float* __restrict__ b6,
                           float* __restrict__ out) {
    const int g = blockIdx.x;
    const int t = threadIdx.x;  // 64 threads
    __shared__ float row[128];
    __shared__ float hid[64];
    row[t] = pooled[g * 128 + t];
    row[64 + t] = pooled[g * 128 + 64 + t];
    __syncthreads();
    float v = b5[t];
    #pragma unroll 8
    for (int c = 0; c < 128; ++c) v = fmaf(row[c], W5[c * 64 + t], v);
    hid[t] = fmaxf(v, 0.f);
    __syncthreads();
    if (t < 10) {
        float o = b6[t];
        #pragma unroll 8
        for (int c = 0; c < 64; ++c) o = fmaf(hid[c], W6[c * 10 + t], o);
        out[g * 10 + t] = o;
    }
}

extern "C" void kernel_launch(void* const* d_in, const int* in_sizes, int n_in,
                              void* d_out, int out_size, void* d_ws, size_t ws_size,
                              hipStream_t stream) {
    const float* x     = (const float*)d_in[0];
    const int*   ei    = (const int*)d_in[1];
    const int*   batch = (const int*)d_in[2];
    const float* W1 = (const float*)d_in[3];  const float* b1 = (const float*)d_in[4];
    const float* W2 = (const float*)d_in[5];  const float* b2 = (const float*)d_in[6];
    const float* W3 = (const float*)d_in[7];  const float* b3 = (const float*)d_in[8];
    const float* W4 = (const float*)d_in[9];  const float* b4 = (const float*)d_in[10];
    const float* W5 = (const float*)d_in[11]; const float* b5 = (const float*)d_in[12];
    const float* W6 = (const float*)d_in[13]; const float* b6 = (const float*)d_in[14];
    float* out = (float*)d_out;

    const int N = in_sizes[0] / 2;       // 100000
    const int E = in_sizes[1] / 2;       // 1600000
    const int G = out_size / 10;         // 512
    const int* src = ei;
    const int* dst = ei + E;

    // workspace layout
    char* p = (char*)d_ws;
    auto take = [&](size_t bytes) -> void* {
        void* r = (void*)p;
        p += (bytes + 255) & ~(size_t)255;
        return r;
    };
    int*   cnt      = (int*)take((size_t)N * 4);
    int*   offs     = (int*)take((size_t)N * 4);
    int*   cursor   = (int*)take((size_t)N * 4);
    int*   bsums    = (int*)take(512 * 4);
    float* dis      = (float*)take((size_t)N * 4);
    int2*  meta     = (int2*)take((size_t)N * 8);
    int*   csr_src  = (int*)take((size_t)E * 4);
    float* csr_norm = (float*)take((size_t)E * 4);
    float* h1       = (float*)take((size_t)N * 16 * 4);
    float* h2       = (float*)take((size_t)N * 32 * 4);
    float* h3       = (float*)take((size_t)N * 64 * 4);
    float* pooled   = (float*)take((size_t)G * 128 * 4);

    hipMemsetAsync(cnt, 0, (size_t)N * 4, stream);
    hipMemsetAsync(pooled, 0, (size_t)G * 128 * 4, stream);

    count_kernel<<<(E + 255) / 256, 256, 0, stream>>>(dst, cnt, E);

    const int NB = (N + 1023) / 1024;    // 98
    scan1_kernel<<<NB, 256, 0, stream>>>(cnt, offs, bsums, dis, N);
    scan2_kernel<<<1, 128, 0, stream>>>(bsums, NB);
    scan3_kernel<<<(N + 255) / 256, 256, 0, stream>>>(offs, bsums, cnt, cursor, meta, N);

    fill_kernel<<<(E + 255) / 256, 256, 0, stream>>>(src, dst, dis, cursor, csr_src, csr_norm, E);

    gcn_l1<<<2048, 256, 0, stream>>>(x, meta, csr_src, csr_norm, dis, W1, b1, h1, N, 2048 * 4);

    const int QBLK = (N + 15) / 16;      // 4 waves x 4 nodes per 256-thr block
    gcn_quad<16, 32, false><<<QBLK, 256, 0, stream>>>(h1, meta, csr_src, csr_norm, dis, W2, b2, h2, nullptr, nullptr, N);
    gcn_quad<32, 64, false><<<QBLK, 256, 0, stream>>>(h2, meta, csr_src, csr_norm, dis, W3, b3, h3, nullptr, nullptr, N);
    gcn_quad<64, 128, true><<<QBLK, 256, 0, stream>>>(h3, meta, csr_src, csr_norm, dis, W4, b4, nullptr, batch, pooled, N);

    mlp_kernel<<<G, 64, 0, stream>>>(pooled, W5, b5, W6, b6, out);
}

// Round 9
// 1173.117 us; speedup vs baseline: 1.6244x; 1.6244x over previous
//
#include <hip/hip_runtime.h>
#include <hip/hip_bf16.h>

typedef __attribute__((ext_vector_type(4))) float f32x4;

// ---------------- degree count ----------------
__global__ void count_kernel(const int* __restrict__ dst, int* __restrict__ cnt, int E) {
    int i = blockIdx.x * blockDim.x + threadIdx.x;
    if (i < E) atomicAdd(&cnt[dst[i]], 1);
}

// ---------------- scan1: block-local exclusive scan + dis = 1/sqrt(deg+1) ----------
__global__ void scan1_kernel(const int* __restrict__ cnt, int* __restrict__ offs,
                             int* __restrict__ bsums, float* __restrict__ dis, int n) {
    const int t = threadIdx.x, lane = t & 63, w = t >> 6;
    const int base = blockIdx.x * 1024 + t * 4;
    int v0 = (base + 0 < n) ? cnt[base + 0] : 0;
    int v1 = (base + 1 < n) ? cnt[base + 1] : 0;
    int v2 = (base + 2 < n) ? cnt[base + 2] : 0;
    int v3 = (base + 3 < n) ? cnt[base + 3] : 0;
    if (base + 0 < n) dis[base + 0] = (float)(1.0 / sqrt((double)(v0 + 1)));
    if (base + 1 < n) dis[base + 1] = (float)(1.0 / sqrt((double)(v1 + 1)));
    if (base + 2 < n) dis[base + 2] = (float)(1.0 / sqrt((double)(v2 + 1)));
    if (base + 3 < n) dis[base + 3] = (float)(1.0 / sqrt((double)(v3 + 1)));
    int s = v0 + v1 + v2 + v3;
    int incl = s;
    #pragma unroll
    for (int off = 1; off < 64; off <<= 1) {
        int y = __shfl_up(incl, off);
        if (lane >= off) incl += y;
    }
    __shared__ int wsum[4];
    if (lane == 63) wsum[w] = incl;
    __syncthreads();
    int wbase = 0;
    #pragma unroll
    for (int k = 0; k < 4; ++k) if (k < w) wbase += wsum[k];
    int run = wbase + incl - s;
    if (base + 0 < n) offs[base + 0] = run; run += v0;
    if (base + 1 < n) offs[base + 1] = run; run += v1;
    if (base + 2 < n) offs[base + 2] = run; run += v2;
    if (base + 3 < n) offs[base + 3] = run;
    if (t == 255) bsums[blockIdx.x] = wbase + incl;
}

__global__ void scan2_kernel(int* __restrict__ bsums, int nb) {
    const int t = threadIdx.x, lane = t & 63, w = t >> 6;  // 128 threads
    int s = (t < nb) ? bsums[t] : 0;
    int incl = s;
    #pragma unroll
    for (int off = 1; off < 64; off <<= 1) {
        int y = __shfl_up(incl, off);
        if (lane >= off) incl += y;
    }
    __shared__ int wsum[2];
    if (lane == 63) wsum[w] = incl;
    __syncthreads();
    int wbase = (w == 1) ? wsum[0] : 0;
    if (t < nb) bsums[t] = wbase + incl - s;
}

// scan3: finalize offsets; emit cursor and packed (start,cnt) meta
__global__ void scan3_kernel(const int* __restrict__ offs, const int* __restrict__ bsums,
                             const int* __restrict__ cnt, int* __restrict__ cursor,
                             int2* __restrict__ meta, int n) {
    int i = blockIdx.x * blockDim.x + threadIdx.x;
    if (i < n) {
        int v = offs[i] + bsums[i >> 10];
        cursor[i] = v;
        meta[i] = make_int2(v, cnt[i]);
    }
}

// ---------------- CSR fill: packed (src, norm) per edge ----------------
__global__ void fill_kernel(const int* __restrict__ src, const int* __restrict__ dst,
                            const float* __restrict__ dis, int* __restrict__ cursor,
                            int2* __restrict__ csr_pk, int E) {
    int i = blockIdx.x * blockDim.x + threadIdx.x;
    if (i < E) {
        int s = src[i], d = dst[i];
        int pos = atomicAdd(&cursor[d], 1);
        csr_pk[pos] = make_int2(s, __float_as_int(dis[s] * dis[d]));
    }
}

// =============== Layer 1: [N,2] -> [N,16]. Persistent wave per node. ==============
__global__ __launch_bounds__(256, 4)
void gcn_l1(const float* __restrict__ x, const int2* __restrict__ meta,
            const int2* __restrict__ csr_pk, const float* __restrict__ dis,
            const float* __restrict__ W, const float* __restrict__ B,
            float* __restrict__ h1, int n, int nwaves) {
    const int lane = threadIdx.x & 63;
    const int wid = blockIdx.x * (blockDim.x >> 6) + (threadIdx.x >> 6);
    const int chunk = (n + nwaves - 1) / nwaves;
    const int n0 = wid * chunk, n1 = min(n0 + chunk, n);
    const int o = lane & 15;
    const float w0 = W[o], w1 = W[16 + o], bo = B[o];
    for (int node = n0; node < n1; ++node) {
        const int2 mt = meta[node];
        const int start = mt.x, m = mt.y;
        float a0 = 0.f, a1 = 0.f;
        for (int j = lane; j < m; j += 64) {
            const int2 pv = csr_pk[start + j];
            const float nm = __int_as_float(pv.y);
            const float2 hv = *(const float2*)(x + 2 * (size_t)pv.x);
            a0 = fmaf(nm, hv.x, a0);
            a1 = fmaf(nm, hv.y, a1);
        }
        #pragma unroll
        for (int off = 32; off >= 1; off >>= 1) {
            a0 += __shfl_xor(a0, off);
            a1 += __shfl_xor(a1, off);
        }
        const float d0 = dis[node], nms = d0 * d0;
        const float2 hs = *(const float2*)(x + 2 * (size_t)node);
        a0 = fmaf(nms, hs.x, a0);
        a1 = fmaf(nms, hs.y, a1);
        if (lane < 16) {
            const float v = fmaf(a0, w0, fmaf(a1, w1, bo));
            h1[(size_t)node * 16 + o] = fmaxf(v, 0.f);
        }
    }
}

// =============== Quad layer: one WAVE computes 4 nodes (NOT unrolled). ============
// Theory (R2-R6): per-node MLP streamed full W through L1<-L2 (32KB/node at
// C64x128) and that, not the gather, was the invariant ~147us. Here W is in LDS
// (no L1 thrash) and every W element serves 4 nodes. Gather = R5-proven asm
// cluster, one node at a time (#pragma unroll 1 -> registers reused, no spill;
// R7/R8 spilled because the gather loop was force-unrolled / W in VGPRs).
template <int C_IN, int C_OUT, bool FPOOL>
__global__ __launch_bounds__(256, 4)
void gcn_quad(const float* __restrict__ h_in, const int2* __restrict__ meta,
              const int2* __restrict__ csr_pk, const float* __restrict__ dis,
              const float* __restrict__ W, const float* __restrict__ Bias,
              float* __restrict__ h_out, const int* __restrict__ batchv,
              float* __restrict__ pooled, int n) {
    constexpr int LPR = C_IN / 4;                      // lanes per row: 4,8,16
    constexpr int EPW = 64 / LPR;                      // edge slots: 16,8,4
    constexpr int LOGL = (LPR == 4) ? 2 : (LPR == 8) ? 3 : 4;
    constexpr int UNROLL = 32 / EPW;                   // 32 slots in flight: 2,4,8
    constexpr int KQ = C_IN / 4;
    constexpr int HALVES = (C_OUT > 64) ? 2 : 1;

    __shared__ float sW[C_IN * C_OUT];
    __shared__ float sB[C_OUT];
    __shared__ float sAgg[4][4][C_IN];                 // [wave][node][ch]

    const int tid = threadIdx.x;
    for (int i = tid; i < C_IN * C_OUT / 4; i += 256)
        ((f32x4*)sW)[i] = ((const f32x4*)W)[i];
    if (tid < C_OUT) sB[tid] = Bias[tid];
    __syncthreads();   // staging done before any wave reads sW (gather phase first anyway)

    const int wave = tid >> 6;
    const int lane = tid & 63;
    const int base = (blockIdx.x * 4 + wave) * 4;      // quad's first node

    const int cb = (lane & (LPR - 1)) * 4;             // channel base
    const int sub = lane >> LOGL;                      // edge slot

    #pragma unroll 1
    for (int nd = 0; nd < 4; ++nd) {                   // sequential: regs reused
        const int node = base + nd;
        const bool valid = node < n;
        const int2 mt = valid ? meta[node] : make_int2(0, 0);
        const int start = mt.x, m = mt.y;
        float ax = 0.f, ay = 0.f, az = 0.f, aw = 0.f;
        for (int j = sub; j < m; j += UNROLL * EPW) {
            int ss[UNROLL]; float nn[UNROLL];
            #pragma unroll
            for (int u = 0; u < UNROLL; ++u) {
                const int jj = j + u * EPW;
                const bool ok = jj < m;
                const int2 pv = csr_pk[start + (ok ? jj : 0)];
                ss[u] = pv.x;
                nn[u] = ok ? __int_as_float(pv.y) : 0.f;
            }
            f32x4 hv[UNROLL];
            const float* ap[UNROLL];
            #pragma unroll
            for (int u = 0; u < UNROLL; ++u) ap[u] = h_in + (size_t)ss[u] * C_IN + cb;
            #pragma unroll
            for (int u = 0; u < UNROLL; ++u)
                asm volatile("global_load_dwordx4 %0, %1, off"
                             : "=v"(hv[u]) : "v"(ap[u]) : "memory");
            asm volatile("s_waitcnt vmcnt(0)" ::: "memory");
            __builtin_amdgcn_sched_barrier(0);         // rule #18
            #pragma unroll
            for (int u = 0; u < UNROLL; ++u) {
                ax = fmaf(nn[u], hv[u].x, ax); ay = fmaf(nn[u], hv[u].y, ay);
                az = fmaf(nn[u], hv[u].z, az); aw = fmaf(nn[u], hv[u].w, aw);
            }
        }
        #pragma unroll
        for (int off = 32; off >= LPR; off >>= 1) {
            ax += __shfl_xor(ax, off); ay += __shfl_xor(ay, off);
            az += __shfl_xor(az, off); aw += __shfl_xor(aw, off);
        }
        if (valid && lane < LPR) {
            const float d0 = dis[node], nms = d0 * d0;
            const f32x4 hs = *(const f32x4*)(h_in + (size_t)node * C_IN + cb);
            ax = fmaf(nms, hs.x, ax); ay = fmaf(nms, hs.y, ay);
            az = fmaf(nms, hs.z, az); aw = fmaf(nms, hs.w, aw);
            f32x4 t; t.x = ax; t.y = ay; t.z = az; t.w = aw;
            *(f32x4*)&sAgg[wave][nd][cb] = t;
        }
    }
    asm volatile("s_waitcnt lgkmcnt(0)" ::: "memory"); // wave-private LDS: no barrier
    __builtin_amdgcn_sched_barrier(0);                 // rule #18

    // ---- node-blocked MLP from LDS: each W element serves 4 nodes ----
    const int oh0 = (C_OUT >= 64) ? lane : (lane & (C_OUT - 1));
    const int oh1 = oh0 + 64;                          // used only if HALVES==2
    const float b0 = sB[oh0];
    const float b1 = (HALVES > 1) ? sB[oh1 < C_OUT ? oh1 : 0] : 0.f;
    float v0[4], v1[4];
    #pragma unroll
    for (int nd = 0; nd < 4; ++nd) { v0[nd] = b0; v1[nd] = b1; }
    #pragma unroll
    for (int kq = 0; kq < KQ; ++kq) {
        f32x4 a[4];
        #pragma unroll
        for (int nd = 0; nd < 4; ++nd)
            a[nd] = *(const f32x4*)&sAgg[wave][nd][kq * 4];
        {
            const float w0 = sW[(kq * 4 + 0) * C_OUT + oh0];
            const float w1 = sW[(kq * 4 + 1) * C_OUT + oh0];
            const float w2 = sW[(kq * 4 + 2) * C_OUT + oh0];
            const float w3 = sW[(kq * 4 + 3) * C_OUT + oh0];
            #pragma unroll
            for (int nd = 0; nd < 4; ++nd) {
                v0[nd] = fmaf(a[nd].x, w0, v0[nd]);
                v0[nd] = fmaf(a[nd].y, w1, v0[nd]);
                v0[nd] = fmaf(a[nd].z, w2, v0[nd]);
                v0[nd] = fmaf(a[nd].w, w3, v0[nd]);
            }
        }
        if constexpr (HALVES > 1) {
            const float w0 = sW[(kq * 4 + 0) * C_OUT + oh1];
            const float w1 = sW[(kq * 4 + 1) * C_OUT + oh1];
            const float w2 = sW[(kq * 4 + 2) * C_OUT + oh1];
            const float w3 = sW[(kq * 4 + 3) * C_OUT + oh1];
            #pragma unroll
            for (int nd = 0; nd < 4; ++nd) {
                v1[nd] = fmaf(a[nd].x, w0, v1[nd]);
                v1[nd] = fmaf(a[nd].y, w1, v1[nd]);
                v1[nd] = fmaf(a[nd].z, w2, v1[nd]);
                v1[nd] = fmaf(a[nd].w, w3, v1[nd]);
            }
        }
    }

    if constexpr (FPOOL) {                             // only with C_OUT==128
        int curg = -1;
        float r0 = 0.f, r1 = 0.f;
        #pragma unroll
        for (int nd = 0; nd < 4; ++nd) {
            const int node = base + nd;
            if (node < n) {
                const int g = batchv[node];
                const float t0 = fmaxf(v0[nd], 0.f);
                const float t1 = fmaxf(v1[nd], 0.f);
                if (g != curg) {
                    if (curg >= 0) {
                        atomicMax((int*)&pooled[(size_t)curg * 128 + oh0], __float_as_int(r0));
                        atomicMax((int*)&pooled[(size_t)curg * 128 + oh1], __float_as_int(r1));
                    }
                    curg = g; r0 = t0; r1 = t1;
                } else {
                    r0 = fmaxf(r0, t0);
                    r1 = fmaxf(r1, t1);
                }
            }
        }
        if (curg >= 0) {
            atomicMax((int*)&pooled[(size_t)curg * 128 + oh0], __float_as_int(r0));
            atomicMax((int*)&pooled[(size_t)curg * 128 + oh1], __float_as_int(r1));
        }
    } else {
        #pragma unroll
        for (int nd = 0; nd < 4; ++nd) {
            const int node = base + nd;
            if (node < n) {
                if (C_OUT >= 64 || lane < C_OUT)
                    h_out[(size_t)node * C_OUT + oh0] = fmaxf(v0[nd], 0.f);
                if (HALVES > 1)
                    h_out[(size_t)node * C_OUT + oh1] = fmaxf(v1[nd], 0.f);
            }
        }
    }
}

// ---------------- MLP head: relu(pooled @ W5 + b5) @ W6 + b6 ----------------
__global__ void mlp_kernel(const float* __restrict__ pooled,
                           const float* __restrict__ W5, const float* __restrict__ b5,
                           const float* __restrict__ W6, const float* __restrict__ b6,
                           float* __restrict__ out) {
    const int g = blockIdx.x;
    const int t = threadIdx.x;  // 64 threads
    __shared__ float row[128];
    __shared__ float hid[64];
    row[t] = pooled[g * 128 + t];
    row[64 + t] = pooled[g * 128 + 64 + t];
    __syncthreads();
    float v = b5[t];
    #pragma unroll 8
    for (int c = 0; c < 128; ++c) v = fmaf(row[c], W5[c * 64 + t], v);
    hid[t] = fmaxf(v, 0.f);
    __syncthreads();
    if (t < 10) {
        float o = b6[t];
        #pragma unroll 8
        for (int c = 0; c < 64; ++c) o = fmaf(hid[c], W6[c * 10 + t], o);
        out[g * 10 + t] = o;
    }
}

extern "C" void kernel_launch(void* const* d_in, const int* in_sizes, int n_in,
                              void* d_out, int out_size, void* d_ws, size_t ws_size,
                              hipStream_t stream) {
    const float* x     = (const float*)d_in[0];
    const int*   ei    = (const int*)d_in[1];
    const int*   batch = (const int*)d_in[2];
    const float* W1 = (const float*)d_in[3];  const float* b1 = (const float*)d_in[4];
    const float* W2 = (const float*)d_in[5];  const float* b2 = (const float*)d_in[6];
    const float* W3 = (const float*)d_in[7];  const float* b3 = (const float*)d_in[8];
    const float* W4 = (const float*)d_in[9];  const float* b4 = (const float*)d_in[10];
    const float* W5 = (const float*)d_in[11]; const float* b5 = (const float*)d_in[12];
    const float* W6 = (const float*)d_in[13]; const float* b6 = (const float*)d_in[14];
    float* out = (float*)d_out;

    const int N = in_sizes[0] / 2;       // 100000
    const int E = in_sizes[1] / 2;       // 1600000
    const int G = out_size / 10;         // 512
    const int* src = ei;
    const int* dst = ei + E;

    // workspace layout
    char* p = (char*)d_ws;
    auto take = [&](size_t bytes) -> void* {
        void* r = (void*)p;
        p += (bytes + 255) & ~(size_t)255;
        return r;
    };
    int*   cnt      = (int*)take((size_t)N * 4);
    int*   offs     = (int*)take((size_t)N * 4);
    int*   cursor   = (int*)take((size_t)N * 4);
    int*   bsums    = (int*)take(512 * 4);
    float* dis      = (float*)take((size_t)N * 4);
    int2*  meta     = (int2*)take((size_t)N * 8);
    int2*  csr_pk   = (int2*)take((size_t)E * 8);
    float* h1       = (float*)take((size_t)N * 16 * 4);
    float* h2       = (float*)take((size_t)N * 32 * 4);
    float* h3       = (float*)take((size_t)N * 64 * 4);
    float* pooled   = (float*)take((size_t)G * 128 * 4);

    hipMemsetAsync(cnt, 0, (size_t)N * 4, stream);
    hipMemsetAsync(pooled, 0, (size_t)G * 128 * 4, stream);

    count_kernel<<<(E + 255) / 256, 256, 0, stream>>>(dst, cnt, E);

    const int NB = (N + 1023) / 1024;    // 98
    scan1_kernel<<<NB, 256, 0, stream>>>(cnt, offs, bsums, dis, N);
    scan2_kernel<<<1, 128, 0, stream>>>(bsums, NB);
    scan3_kernel<<<(N + 255) / 256, 256, 0, stream>>>(offs, bsums, cnt, cursor, meta, N);

    fill_kernel<<<(E + 255) / 256, 256, 0, stream>>>(src, dst, dis, cursor, csr_pk, E);

    gcn_l1<<<2048, 256, 0, stream>>>(x, meta, csr_pk, dis, W1, b1, h1, N, 2048 * 4);

    const int QBLK = (N + 15) / 16;      // 4 waves x 4 nodes per 256-thr block
    gcn_quad<16, 32, false><<<QBLK, 256, 0, stream>>>(h1, meta, csr_pk, dis, W2, b2, h2, nullptr, nullptr, N);
    gcn_quad<32, 64, false><<<QBLK, 256, 0, stream>>>(h2, meta, csr_pk, dis, W3, b3, h3, nullptr, nullptr, N);
    gcn_quad<64, 128, true><<<QBLK, 256, 0, stream>>>(h3, meta, csr_pk, dis, W4, b4, nullptr, batch, pooled, N);

    mlp_kernel<<<G, 64, 0, stream>>>(pooled, W5, b5, W6, b6, out);
}

// Round 10
// 497.775 us; speedup vs baseline: 3.8283x; 2.3567x over previous
//
#include <hip/hip_runtime.h>
#include <hip/hip_bf16.h>

typedef __attribute__((ext_vector_type(4))) float f32x4;

// ---------------- degree count ----------------
__global__ void count_kernel(const int* __restrict__ dst, int* __restrict__ cnt, int E) {
    int i = blockIdx.x * blockDim.x + threadIdx.x;
    if (i < E) atomicAdd(&cnt[dst[i]], 1);
}

// ---------------- scan1: block-local exclusive scan + dis = 1/sqrt(deg+1) ----------
__global__ void scan1_kernel(const int* __restrict__ cnt, int* __restrict__ offs,
                             int* __restrict__ bsums, float* __restrict__ dis, int n) {
    const int t = threadIdx.x, lane = t & 63, w = t >> 6;
    const int base = blockIdx.x * 1024 + t * 4;
    int v0 = (base + 0 < n) ? cnt[base + 0] : 0;
    int v1 = (base + 1 < n) ? cnt[base + 1] : 0;
    int v2 = (base + 2 < n) ? cnt[base + 2] : 0;
    int v3 = (base + 3 < n) ? cnt[base + 3] : 0;
    if (base + 0 < n) dis[base + 0] = (float)(1.0 / sqrt((double)(v0 + 1)));
    if (base + 1 < n) dis[base + 1] = (float)(1.0 / sqrt((double)(v1 + 1)));
    if (base + 2 < n) dis[base + 2] = (float)(1.0 / sqrt((double)(v2 + 1)));
    if (base + 3 < n) dis[base + 3] = (float)(1.0 / sqrt((double)(v3 + 1)));
    int s = v0 + v1 + v2 + v3;
    int incl = s;
    #pragma unroll
    for (int off = 1; off < 64; off <<= 1) {
        int y = __shfl_up(incl, off);
        if (lane >= off) incl += y;
    }
    __shared__ int wsum[4];
    if (lane == 63) wsum[w] = incl;
    __syncthreads();
    int wbase = 0;
    #pragma unroll
    for (int k = 0; k < 4; ++k) if (k < w) wbase += wsum[k];
    int run = wbase + incl - s;
    if (base + 0 < n) offs[base + 0] = run; run += v0;
    if (base + 1 < n) offs[base + 1] = run; run += v1;
    if (base + 2 < n) offs[base + 2] = run; run += v2;
    if (base + 3 < n) offs[base + 3] = run;
    if (t == 255) bsums[blockIdx.x] = wbase + incl;
}

__global__ void scan2_kernel(int* __restrict__ bsums, int nb) {
    const int t = threadIdx.x, lane = t & 63, w = t >> 6;  // 128 threads
    int s = (t < nb) ? bsums[t] : 0;
    int incl = s;
    #pragma unroll
    for (int off = 1; off < 64; off <<= 1) {
        int y = __shfl_up(incl, off);
        if (lane >= off) incl += y;
    }
    __shared__ int wsum[2];
    if (lane == 63) wsum[w] = incl;
    __syncthreads();
    int wbase = (w == 1) ? wsum[0] : 0;
    if (t < nb) bsums[t] = wbase + incl - s;
}

// scan3: finalize offsets; emit cursor and packed (start,cnt) meta
__global__ void scan3_kernel(const int* __restrict__ offs, const int* __restrict__ bsums,
                             const int* __restrict__ cnt, int* __restrict__ cursor,
                             int2* __restrict__ meta, int n) {
    int i = blockIdx.x * blockDim.x + threadIdx.x;
    if (i < n) {
        int v = offs[i] + bsums[i >> 10];
        cursor[i] = v;
        meta[i] = make_int2(v, cnt[i]);
    }
}

// ---------------- CSR fill: packed (src, norm) per edge ----------------
__global__ void fill_kernel(const int* __restrict__ src, const int* __restrict__ dst,
                            const float* __restrict__ dis, int* __restrict__ cursor,
                            int2* __restrict__ csr_pk, int E) {
    int i = blockIdx.x * blockDim.x + threadIdx.x;
    if (i < E) {
        int s = src[i], d = dst[i];
        int pos = atomicAdd(&cursor[d], 1);
        csr_pk[pos] = make_int2(s, __float_as_int(dis[s] * dis[d]));
    }
}

// =============== Layer 1: [N,2] -> [N,16]. Persistent wave per node. ==============
__global__ __launch_bounds__(256, 4)
void gcn_l1(const float* __restrict__ x, const int2* __restrict__ meta,
            const int2* __restrict__ csr_pk, const float* __restrict__ dis,
            const float* __restrict__ W, const float* __restrict__ B,
            float* __restrict__ h1, int n, int nwaves) {
    const int lane = threadIdx.x & 63;
    const int wid = blockIdx.x * (blockDim.x >> 6) + (threadIdx.x >> 6);
    const int chunk = (n + nwaves - 1) / nwaves;
    const int n0 = wid * chunk, n1 = min(n0 + chunk, n);
    const int o = lane & 15;
    const float w0 = W[o], w1 = W[16 + o], bo = B[o];
    for (int node = n0; node < n1; ++node) {
        const int2 mt = meta[node];
        const int start = mt.x, m = mt.y;
        float a0 = 0.f, a1 = 0.f;
        for (int j = lane; j < m; j += 64) {
            const int2 pv = csr_pk[start + j];
            const float nm = __int_as_float(pv.y);
            const float2 hv = *(const float2*)(x + 2 * (size_t)pv.x);
            a0 = fmaf(nm, hv.x, a0);
            a1 = fmaf(nm, hv.y, a1);
        }
        #pragma unroll
        for (int off = 32; off >= 1; off >>= 1) {
            a0 += __shfl_xor(a0, off);
            a1 += __shfl_xor(a1, off);
        }
        const float d0 = dis[node], nms = d0 * d0;
        const float2 hs = *(const float2*)(x + 2 * (size_t)node);
        a0 = fmaf(nms, hs.x, a0);
        a1 = fmaf(nms, hs.y, a1);
        if (lane < 16) {
            const float v = fmaf(a0, w0, fmaf(a1, w1, bo));
            h1[(size_t)node * 16 + o] = fmaxf(v, 0.f);
        }
    }
}

// =============== AGG: pure gather+normalize. One wave per node, ZERO LDS, =========
// ZERO barriers, hv[4] only (~45 VGPR -> 8 waves/SIMD). Writes agg[N][C_IN].
template <int C_IN>
__global__ __launch_bounds__(128, 8)
void agg_kernel(const float* __restrict__ h_in, const int2* __restrict__ meta,
                const int2* __restrict__ csr_pk, const float* __restrict__ dis,
                float* __restrict__ agg, int n) {
    constexpr int LPR = C_IN / 4;                      // 4, 8, 16
    constexpr int EPW = 64 / LPR;                      // 16, 8, 4
    constexpr int LOGL = (LPR == 4) ? 2 : (LPR == 8) ? 3 : 4;

    const int lane = threadIdx.x & 63;
    const int node = blockIdx.x * 2 + (threadIdx.x >> 6);
    if (node >= n) return;

    const int2 mt = meta[node];
    const int start = mt.x, m = mt.y;
    const int cb = (lane & (LPR - 1)) * 4;
    const int sub = lane >> LOGL;

    float ax = 0.f, ay = 0.f, az = 0.f, aw = 0.f;
    for (int j = sub; j < m; j += 4 * EPW) {
        int ss0, ss1, ss2, ss3;
        float nn0, nn1, nn2, nn3;
        {
            const bool ok1 = j + 1 * EPW < m, ok2 = j + 2 * EPW < m, ok3 = j + 3 * EPW < m;
            const int2 p0 = csr_pk[start + j];
            const int2 p1 = csr_pk[start + (ok1 ? j + 1 * EPW : 0)];
            const int2 p2 = csr_pk[start + (ok2 ? j + 2 * EPW : 0)];
            const int2 p3 = csr_pk[start + (ok3 ? j + 3 * EPW : 0)];
            ss0 = p0.x; nn0 = __int_as_float(p0.y);
            ss1 = p1.x; nn1 = ok1 ? __int_as_float(p1.y) : 0.f;
            ss2 = p2.x; nn2 = ok2 ? __int_as_float(p2.y) : 0.f;
            ss3 = p3.x; nn3 = ok3 ? __int_as_float(p3.y) : 0.f;
        }
        f32x4 h0, h1v, h2v, h3v;
        const float* a0 = h_in + (size_t)ss0 * C_IN + cb;
        const float* a1 = h_in + (size_t)ss1 * C_IN + cb;
        const float* a2 = h_in + (size_t)ss2 * C_IN + cb;
        const float* a3 = h_in + (size_t)ss3 * C_IN + cb;
        asm volatile("global_load_dwordx4 %0, %1, off" : "=v"(h0)  : "v"(a0) : "memory");
        asm volatile("global_load_dwordx4 %0, %1, off" : "=v"(h1v) : "v"(a1) : "memory");
        asm volatile("global_load_dwordx4 %0, %1, off" : "=v"(h2v) : "v"(a2) : "memory");
        asm volatile("global_load_dwordx4 %0, %1, off" : "=v"(h3v) : "v"(a3) : "memory");
        asm volatile("s_waitcnt vmcnt(0)" ::: "memory");
        __builtin_amdgcn_sched_barrier(0);             // rule #18
        ax = fmaf(nn0, h0.x, ax);  ay = fmaf(nn0, h0.y, ay);
        az = fmaf(nn0, h0.z, az);  aw = fmaf(nn0, h0.w, aw);
        ax = fmaf(nn1, h1v.x, ax); ay = fmaf(nn1, h1v.y, ay);
        az = fmaf(nn1, h1v.z, az); aw = fmaf(nn1, h1v.w, aw);
        ax = fmaf(nn2, h2v.x, ax); ay = fmaf(nn2, h2v.y, ay);
        az = fmaf(nn2, h2v.z, az); aw = fmaf(nn2, h2v.w, aw);
        ax = fmaf(nn3, h3v.x, ax); ay = fmaf(nn3, h3v.y, ay);
        az = fmaf(nn3, h3v.z, az); aw = fmaf(nn3, h3v.w, aw);
    }
    #pragma unroll
    for (int off = 32; off >= LPR; off >>= 1) {
        ax += __shfl_xor(ax, off); ay += __shfl_xor(ay, off);
        az += __shfl_xor(az, off); aw += __shfl_xor(aw, off);
    }
    if (lane < LPR) {
        const float d0 = dis[node], nms = d0 * d0;
        const f32x4 hs = *(const f32x4*)(h_in + (size_t)node * C_IN + cb);
        ax = fmaf(nms, hs.x, ax); ay = fmaf(nms, hs.y, ay);
        az = fmaf(nms, hs.z, az); aw = fmaf(nms, hs.w, aw);
        f32x4 t; t.x = ax; t.y = ay; t.z = az; t.w = aw;
        *(f32x4*)&agg[(size_t)node * C_IN + cb] = t;
    }
}

// =============== GEMM: h_out = relu(agg @ W + B). 64-node tile per block. =========
// W staged in LDS; each W read broadcast-serves 16 nodes (the reuse the fused
// kernels lacked). FPOOL: epilogue max-pools the contiguous 64-node tile in LDS.
template <int C_IN, int C_OUT, bool FPOOL>
__global__ __launch_bounds__(256, 3)
void gemm_kernel(const float* __restrict__ agg, const float* __restrict__ W,
                 const float* __restrict__ Bias, float* __restrict__ h_out,
                 const int* __restrict__ batchv, float* __restrict__ pooled, int n) {
    constexpr int STRIDE = C_IN + 4;                   // 16B-aligned pad
    constexpr int OPG = C_OUT / 4;                     // outs per group: 8,16,32
    constexpr int JN = OPG / 4;                        // f32x4 accs: 2,4,8
    constexpr int CH = C_IN / 4;                       // row chunks: 4,8,16

    __shared__ float sW[C_IN * C_OUT];
    __shared__ float sB[C_OUT];
    __shared__ float sA[64 * STRIDE];
    __shared__ int sGb[64];

    const int tid = threadIdx.x;
    const int base = blockIdx.x * 64;

    for (int idx = tid; idx < C_IN * C_OUT / 4; idx += 256)
        ((f32x4*)sW)[idx] = ((const f32x4*)W)[idx];
    if (tid < C_OUT) sB[tid] = Bias[tid];
    {   // stage agg rows (zero-padded past n)
        const int r0 = tid / CH, c0 = tid % CH;
        constexpr int RPP = 256 / CH;
        #pragma unroll
        for (int p = 0; p < 64 / RPP; ++p) {
            const int r = p * RPP + r0;
            const int node = base + r;
            f32x4 v = {0.f, 0.f, 0.f, 0.f};
            if (node < n) v = *(const f32x4*)&agg[(size_t)node * C_IN + c0 * 4];
            *(f32x4*)&sA[r * STRIDE + c0 * 4] = v;
        }
    }
    if (FPOOL && tid < 64) sGb[tid] = (base + tid < n) ? batchv[base + tid] : -1;
    __syncthreads();

    const int i = tid >> 2;        // node row 0..63
    const int g = tid & 3;         // out group 0..3
    const f32x4* sWv = (const f32x4*)sW;

    f32x4 acc[JN];
    #pragma unroll
    for (int j = 0; j < JN; ++j) acc[j] = *(const f32x4*)&sB[g * OPG + j * 4];

    #pragma unroll 8
    for (int k = 0; k < C_IN; ++k) {
        const float av = sA[i * STRIDE + k];
        #pragma unroll
        for (int j = 0; j < JN; ++j) {
            const f32x4 wv = sWv[k * (C_OUT / 4) + g * JN + j];
            acc[j].x = fmaf(av, wv.x, acc[j].x);
            acc[j].y = fmaf(av, wv.y, acc[j].y);
            acc[j].z = fmaf(av, wv.z, acc[j].z);
            acc[j].w = fmaf(av, wv.w, acc[j].w);
        }
    }

    if constexpr (!FPOOL) {
        const int node = base + i;
        if (node < n) {
            #pragma unroll
            for (int j = 0; j < JN; ++j) {
                f32x4 r;
                r.x = fmaxf(acc[j].x, 0.f); r.y = fmaxf(acc[j].y, 0.f);
                r.z = fmaxf(acc[j].z, 0.f); r.w = fmaxf(acc[j].w, 0.f);
                *(f32x4*)&h_out[(size_t)node * C_OUT + g * OPG + j * 4] = r;
            }
        }
    } else {
        // epilogue pool: 4 passes, one out-group at a time, via sA-overlaid sP
        float* sP = sA;                               // 64 x 36 (stride 36, 16B ok)
        #pragma unroll 1
        for (int p = 0; p < 4; ++p) {
            __syncthreads();                          // prior pass reads / k-loop done
            if (g == p) {
                #pragma unroll
                for (int j = 0; j < JN; ++j) {
                    f32x4 r;
                    r.x = fmaxf(acc[j].x, 0.f); r.y = fmaxf(acc[j].y, 0.f);
                    r.z = fmaxf(acc[j].z, 0.f); r.w = fmaxf(acc[j].w, 0.f);
                    *(f32x4*)&sP[i * 36 + j * 4] = r;
                }
            }
            __syncthreads();
            if (tid < 32) {                           // one thread per out column
                const int c = tid;
                int curg = -1; float run = 0.f;
                for (int r = 0; r < 64; ++r) {
                    const int gb = sGb[r];
                    if (gb < 0) continue;
                    const float v = sP[r * 36 + c];
                    if (gb != curg) {
                        if (curg >= 0)
                            atomicMax((int*)&pooled[(size_t)curg * 128 + p * 32 + c],
                                      __float_as_int(run));
                        curg = gb; run = v;
                    } else {
                        run = fmaxf(run, v);
                    }
                }
                if (curg >= 0)
                    atomicMax((int*)&pooled[(size_t)curg * 128 + p * 32 + c],
                              __float_as_int(run));
            }
        }
    }
}

// ---------------- MLP head: relu(pooled @ W5 + b5) @ W6 + b6 ----------------
__global__ void mlp_kernel(const float* __restrict__ pooled,
                           const float* __restrict__ W5, const float* __restrict__ b5,
                           const float* __restrict__ W6, const float* __restrict__ b6,
                           float* __restrict__ out) {
    const int g = blockIdx.x;
    const int t = threadIdx.x;  // 64 threads
    __shared__ float row[128];
    __shared__ float hid[64];
    row[t] = pooled[g * 128 + t];
    row[64 + t] = pooled[g * 128 + 64 + t];
    __syncthreads();
    float v = b5[t];
    #pragma unroll 8
    for (int c = 0; c < 128; ++c) v = fmaf(row[c], W5[c * 64 + t], v);
    hid[t] = fmaxf(v, 0.f);
    __syncthreads();
    if (t < 10) {
        float o = b6[t];
        #pragma unroll 8
        for (int c = 0; c < 64; ++c) o = fmaf(hid[c], W6[c * 10 + t], o);
        out[g * 10 + t] = o;
    }
}

extern "C" void kernel_launch(void* const* d_in, const int* in_sizes, int n_in,
                              void* d_out, int out_size, void* d_ws, size_t ws_size,
                              hipStream_t stream) {
    const float* x     = (const float*)d_in[0];
    const int*   ei    = (const int*)d_in[1];
    const int*   batch = (const int*)d_in[2];
    const float* W1 = (const float*)d_in[3];  const float* b1 = (const float*)d_in[4];
    const float* W2 = (const float*)d_in[5];  const float* b2 = (const float*)d_in[6];
    const float* W3 = (const float*)d_in[7];  const float* b3 = (const float*)d_in[8];
    const float* W4 = (const float*)d_in[9];  const float* b4 = (const float*)d_in[10];
    const float* W5 = (const float*)d_in[11]; const float* b5 = (const float*)d_in[12];
    const float* W6 = (const float*)d_in[13]; const float* b6 = (const float*)d_in[14];
    float* out = (float*)d_out;

    const int N = in_sizes[0] / 2;       // 100000
    const int E = in_sizes[1] / 2;       // 1600000
    const int G = out_size / 10;         // 512
    const int* src = ei;
    const int* dst = ei + E;

    // workspace layout (~85 MB)
    char* p = (char*)d_ws;
    auto take = [&](size_t bytes) -> void* {
        void* r = (void*)p;
        p += (bytes + 255) & ~(size_t)255;
        return r;
    };
    int*   cnt      = (int*)take((size_t)N * 4);
    int*   offs     = (int*)take((size_t)N * 4);
    int*   cursor   = (int*)take((size_t)N * 4);
    int*   bsums    = (int*)take(512 * 4);
    float* dis      = (float*)take((size_t)N * 4);
    int2*  meta     = (int2*)take((size_t)N * 8);
    int2*  csr_pk   = (int2*)take((size_t)E * 8);
    float* h1       = (float*)take((size_t)N * 16 * 4);
    float* h2       = (float*)take((size_t)N * 32 * 4);
    float* h3       = (float*)take((size_t)N * 64 * 4);
    float* aggb     = (float*)take((size_t)N * 64 * 4);   // shared agg buffer (max C_IN=64)
    float* pooled   = (float*)take((size_t)G * 128 * 4);

    hipMemsetAsync(cnt, 0, (size_t)N * 4, stream);
    hipMemsetAsync(pooled, 0, (size_t)G * 128 * 4, stream);

    count_kernel<<<(E + 255) / 256, 256, 0, stream>>>(dst, cnt, E);

    const int NB = (N + 1023) / 1024;    // 98
    scan1_kernel<<<NB, 256, 0, stream>>>(cnt, offs, bsums, dis, N);
    scan2_kernel<<<1, 128, 0, stream>>>(bsums, NB);
    scan3_kernel<<<(N + 255) / 256, 256, 0, stream>>>(offs, bsums, cnt, cursor, meta, N);

    fill_kernel<<<(E + 255) / 256, 256, 0, stream>>>(src, dst, dis, cursor, csr_pk, E);

    gcn_l1<<<2048, 256, 0, stream>>>(x, meta, csr_pk, dis, W1, b1, h1, N, 2048 * 4);

    const int ABLK = (N + 1) / 2;        // 2 waves per 128-thr block, 1 node each
    const int GBLK = (N + 63) / 64;      // 64-node GEMM tiles

    agg_kernel<16><<<ABLK, 128, 0, stream>>>(h1, meta, csr_pk, dis, aggb, N);
    gemm_kernel<16, 32, false><<<GBLK, 256, 0, stream>>>(aggb, W2, b2, h2, nullptr, nullptr, N);

    agg_kernel<32><<<ABLK, 128, 0, stream>>>(h2, meta, csr_pk, dis, aggb, N);
    gemm_kernel<32, 64, false><<<GBLK, 256, 0, stream>>>(aggb, W3, b3, h3, nullptr, nullptr, N);

    agg_kernel<64><<<ABLK, 128, 0, stream>>>(h3, meta, csr_pk, dis, aggb, N);
    gemm_kernel<64, 128, true><<<GBLK, 256, 0, stream>>>(aggb, W4, b4, nullptr, batch, pooled, N);

    mlp_kernel<<<G, 64, 0, stream>>>(pooled, W5, b5, W6, b6, out);
}

// Round 11
// 400.287 us; speedup vs baseline: 4.7606x; 1.2435x over previous
//
#include <hip/hip_runtime.h>
#include <hip/hip_bf16.h>

typedef __attribute__((ext_vector_type(4))) float f32x4;

// ---------------- degree count ----------------
__global__ void count_kernel(const int* __restrict__ dst, int* __restrict__ cnt, int E) {
    int i = blockIdx.x * blockDim.x + threadIdx.x;
    if (i < E) atomicAdd(&cnt[dst[i]], 1);
}

// ---------------- scan1: block-local exclusive scan + dis = 1/sqrt(deg+1) ----------
__global__ void scan1_kernel(const int* __restrict__ cnt, int* __restrict__ offs,
                             int* __restrict__ bsums, float* __restrict__ dis, int n) {
    const int t = threadIdx.x, lane = t & 63, w = t >> 6;
    const int base = blockIdx.x * 1024 + t * 4;
    int v0 = (base + 0 < n) ? cnt[base + 0] : 0;
    int v1 = (base + 1 < n) ? cnt[base + 1] : 0;
    int v2 = (base + 2 < n) ? cnt[base + 2] : 0;
    int v3 = (base + 3 < n) ? cnt[base + 3] : 0;
    if (base + 0 < n) dis[base + 0] = (float)(1.0 / sqrt((double)(v0 + 1)));
    if (base + 1 < n) dis[base + 1] = (float)(1.0 / sqrt((double)(v1 + 1)));
    if (base + 2 < n) dis[base + 2] = (float)(1.0 / sqrt((double)(v2 + 1)));
    if (base + 3 < n) dis[base + 3] = (float)(1.0 / sqrt((double)(v3 + 1)));
    int s = v0 + v1 + v2 + v3;
    int incl = s;
    #pragma unroll
    for (int off = 1; off < 64; off <<= 1) {
        int y = __shfl_up(incl, off);
        if (lane >= off) incl += y;
    }
    __shared__ int wsum[4];
    if (lane == 63) wsum[w] = incl;
    __syncthreads();
    int wbase = 0;
    #pragma unroll
    for (int k = 0; k < 4; ++k) if (k < w) wbase += wsum[k];
    int run = wbase + incl - s;
    if (base + 0 < n) offs[base + 0] = run; run += v0;
    if (base + 1 < n) offs[base + 1] = run; run += v1;
    if (base + 2 < n) offs[base + 2] = run; run += v2;
    if (base + 3 < n) offs[base + 3] = run;
    if (t == 255) bsums[blockIdx.x] = wbase + incl;
}

__global__ void scan2_kernel(int* __restrict__ bsums, int nb) {
    const int t = threadIdx.x, lane = t & 63, w = t >> 6;  // 128 threads
    int s = (t < nb) ? bsums[t] : 0;
    int incl = s;
    #pragma unroll
    for (int off = 1; off < 64; off <<= 1) {
        int y = __shfl_up(incl, off);
        if (lane >= off) incl += y;
    }
    __shared__ int wsum[2];
    if (lane == 63) wsum[w] = incl;
    __syncthreads();
    int wbase = (w == 1) ? wsum[0] : 0;
    if (t < nb) bsums[t] = wbase + incl - s;
}

// scan3: finalize offsets; emit cursor and packed (start,cnt) meta
__global__ void scan3_kernel(const int* __restrict__ offs, const int* __restrict__ bsums,
                             const int* __restrict__ cnt, int* __restrict__ cursor,
                             int2* __restrict__ meta, int n) {
    int i = blockIdx.x * blockDim.x + threadIdx.x;
    if (i < n) {
        int v = offs[i] + bsums[i >> 10];
        cursor[i] = v;
        meta[i] = make_int2(v, cnt[i]);
    }
}

// ---------------- CSR fill: packed (src, norm) per edge ----------------
__global__ void fill_kernel(const int* __restrict__ src, const int* __restrict__ dst,
                            const float* __restrict__ dis, int* __restrict__ cursor,
                            int2* __restrict__ csr_pk, int E) {
    int i = blockIdx.x * blockDim.x + threadIdx.x;
    if (i < E) {
        int s = src[i], d = dst[i];
        int pos = atomicAdd(&cursor[d], 1);
        csr_pk[pos] = make_int2(s, __float_as_int(dis[s] * dis[d]));
    }
}

// =============== Layer 1: [N,2] -> [N,16]. Persistent wave per node. ==============
__global__ __launch_bounds__(256, 4)
void gcn_l1(const float* __restrict__ x, const int2* __restrict__ meta,
            const int2* __restrict__ csr_pk, const float* __restrict__ dis,
            const float* __restrict__ W, const float* __restrict__ B,
            float* __restrict__ h1, int n, int nwaves) {
    const int lane = threadIdx.x & 63;
    const int wid = blockIdx.x * (blockDim.x >> 6) + (threadIdx.x >> 6);
    const int chunk = (n + nwaves - 1) / nwaves;
    const int n0 = wid * chunk, n1 = min(n0 + chunk, n);
    const int o = lane & 15;
    const float w0 = W[o], w1 = W[16 + o], bo = B[o];
    for (int node = n0; node < n1; ++node) {
        const int2 mt = meta[node];
        const int start = mt.x, m = mt.y;
        float a0 = 0.f, a1 = 0.f;
        for (int j = lane; j < m; j += 64) {
            const int2 pv = csr_pk[start + j];
            const float nm = __int_as_float(pv.y);
            const float2 hv = *(const float2*)(x + 2 * (size_t)pv.x);
            a0 = fmaf(nm, hv.x, a0);
            a1 = fmaf(nm, hv.y, a1);
        }
        #pragma unroll
        for (int off = 32; off >= 1; off >>= 1) {
            a0 += __shfl_xor(a0, off);
            a1 += __shfl_xor(a1, off);
        }
        const float d0 = dis[node], nms = d0 * d0;
        const float2 hs = *(const float2*)(x + 2 * (size_t)node);
        a0 = fmaf(nms, hs.x, a0);
        a1 = fmaf(nms, hs.y, a1);
        if (lane < 16) {
            const float v = fmaf(a0, w0, fmaf(a1, w1, bo));
            h1[(size_t)node * 16 + o] = fmaxf(v, 0.f);
        }
    }
}

// =============== AGG: pure gather+normalize. One wave per node, zero barriers. ====
template <int C_IN>
__global__ __launch_bounds__(256, 8)
void agg_kernel(const float* __restrict__ h_in, const int2* __restrict__ meta,
                const int2* __restrict__ csr_pk, const float* __restrict__ dis,
                float* __restrict__ agg, int n) {
    constexpr int LPR = C_IN / 4;                      // 4, 8, 16
    constexpr int EPW = 64 / LPR;                      // 16, 8, 4
    constexpr int LOGL = (LPR == 4) ? 2 : (LPR == 8) ? 3 : 4;

    const int lane = threadIdx.x & 63;
    const int node = blockIdx.x * 4 + (threadIdx.x >> 6);
    if (node >= n) return;

    const int2 mt = meta[node];
    const int start = mt.x, m = mt.y;
    const int cb = (lane & (LPR - 1)) * 4;
    const int sub = lane >> LOGL;

    float ax = 0.f, ay = 0.f, az = 0.f, aw = 0.f;
    for (int j = sub; j < m; j += 4 * EPW) {
        int ss0, ss1, ss2, ss3;
        float nn0, nn1, nn2, nn3;
        {
            const bool ok1 = j + 1 * EPW < m, ok2 = j + 2 * EPW < m, ok3 = j + 3 * EPW < m;
            const int2 p0 = csr_pk[start + j];
            const int2 p1 = csr_pk[start + (ok1 ? j + 1 * EPW : 0)];
            const int2 p2 = csr_pk[start + (ok2 ? j + 2 * EPW : 0)];
            const int2 p3 = csr_pk[start + (ok3 ? j + 3 * EPW : 0)];
            ss0 = p0.x; nn0 = __int_as_float(p0.y);
            ss1 = p1.x; nn1 = ok1 ? __int_as_float(p1.y) : 0.f;
            ss2 = p2.x; nn2 = ok2 ? __int_as_float(p2.y) : 0.f;
            ss3 = p3.x; nn3 = ok3 ? __int_as_float(p3.y) : 0.f;
        }
        f32x4 h0, h1v, h2v, h3v;
        const float* a0 = h_in + (size_t)ss0 * C_IN + cb;
        const float* a1 = h_in + (size_t)ss1 * C_IN + cb;
        const float* a2 = h_in + (size_t)ss2 * C_IN + cb;
        const float* a3 = h_in + (size_t)ss3 * C_IN + cb;
        asm volatile("global_load_dwordx4 %0, %1, off" : "=v"(h0)  : "v"(a0) : "memory");
        asm volatile("global_load_dwordx4 %0, %1, off" : "=v"(h1v) : "v"(a1) : "memory");
        asm volatile("global_load_dwordx4 %0, %1, off" : "=v"(h2v) : "v"(a2) : "memory");
        asm volatile("global_load_dwordx4 %0, %1, off" : "=v"(h3v) : "v"(a3) : "memory");
        asm volatile("s_waitcnt vmcnt(0)" ::: "memory");
        __builtin_amdgcn_sched_barrier(0);             // rule #18
        ax = fmaf(nn0, h0.x, ax);  ay = fmaf(nn0, h0.y, ay);
        az = fmaf(nn0, h0.z, az);  aw = fmaf(nn0, h0.w, aw);
        ax = fmaf(nn1, h1v.x, ax); ay = fmaf(nn1, h1v.y, ay);
        az = fmaf(nn1, h1v.z, az); aw = fmaf(nn1, h1v.w, aw);
        ax = fmaf(nn2, h2v.x, ax); ay = fmaf(nn2, h2v.y, ay);
        az = fmaf(nn2, h2v.z, az); aw = fmaf(nn2, h2v.w, aw);
        ax = fmaf(nn3, h3v.x, ax); ay = fmaf(nn3, h3v.y, ay);
        az = fmaf(nn3, h3v.z, az); aw = fmaf(nn3, h3v.w, aw);
    }
    #pragma unroll
    for (int off = 32; off >= LPR; off >>= 1) {
        ax += __shfl_xor(ax, off); ay += __shfl_xor(ay, off);
        az += __shfl_xor(az, off); aw += __shfl_xor(aw, off);
    }
    if (lane < LPR) {
        const float d0 = dis[node], nms = d0 * d0;
        const f32x4 hs = *(const f32x4*)(h_in + (size_t)node * C_IN + cb);
        ax = fmaf(nms, hs.x, ax); ay = fmaf(nms, hs.y, ay);
        az = fmaf(nms, hs.z, az); aw = fmaf(nms, hs.w, aw);
        f32x4 t; t.x = ax; t.y = ay; t.z = az; t.w = aw;
        *(f32x4*)&agg[(size_t)node * C_IN + cb] = t;
    }
}

// =============== GEMM: h_out = relu(agg @ W + B). 64-node tile, LDS-lean. =========
// R10 lesson: old mapping was LDS-instruction-bound (9 LDS instrs/k/wave, 1.3e7
// bank conflicts). New mapping: thread owns RPT=C_OUT/16 rows x 4 outs; per k:
// 1 W b128 + RPT/4 A b128 (A stored TRANSPOSED At[k][row], stride 68) -> 2-3 LDS
// instrs/k/wave, all conflict-free (W banks tile 4j; At 2-way only). VALU-bound.
template <int C_IN, int C_OUT, bool FPOOL>
__global__ __launch_bounds__(256, 3)
void gemm_kernel(const float* __restrict__ agg, const float* __restrict__ W,
                 const float* __restrict__ Bias, float* __restrict__ h_out,
                 const int* __restrict__ batchv, float* __restrict__ pooled, int n) {
    constexpr int QW = C_OUT / 16;                 // out-quads per wave: 2,4,8
    constexpr int RPT = QW;                        // rows per thread: 2,4,8
    constexpr int LOGQ = (QW == 8) ? 3 : (QW == 4) ? 2 : 1;
    constexpr int CH = C_IN / 4;                   // f32x4 chunks per agg row
    constexpr int SA = 68;                         // At row stride (64 rows + pad)
    constexpr int SP = 133;                        // sP row stride (conflict-free b32)

    constexpr int W_BYTES = C_IN * C_OUT * 4 + C_OUT * 4;      // sW + sB
    constexpr int P_BYTES = FPOOL ? (64 * SP * 4) : 0;
    constexpr int R1 = (W_BYTES > P_BYTES ? W_BYTES : P_BYTES + 15) & ~15;
    constexpr int AT_BYTES = C_IN * SA * 4;
    __shared__ char smem[R1 + AT_BYTES + 256];

    float* sW = (float*)smem;                      // [C_IN*C_OUT]
    float* sB = sW + C_IN * C_OUT;                 // [C_OUT]
    float* sP = (float*)smem;                      // overlays sW after k-loop (FPOOL)
    float* sAt = (float*)(smem + R1);              // [C_IN][68]
    int*   sGb = (int*)(smem + R1 + AT_BYTES);     // [64]

    const int tid = threadIdx.x;
    const int base = blockIdx.x * 64;

    for (int i = tid; i < C_IN * C_OUT / 4; i += 256)
        ((f32x4*)sW)[i] = ((const f32x4*)W)[i];
    if (tid < C_OUT) sB[tid] = Bias[tid];
    {   // stage agg transposed: At[k][row] (zero past n). 4 b32 writes per chunk.
        constexpr int RPP = 256 / CH;              // rows per pass: 64,32,16
        const int r = tid / CH, c0 = tid % CH;
        #pragma unroll
        for (int p = 0; p < 64 / RPP; ++p) {
            const int rr = p * RPP + r;
            const int node = base + rr;
            f32x4 v = {0.f, 0.f, 0.f, 0.f};
            if (node < n) v = *(const f32x4*)&agg[(size_t)node * C_IN + c0 * 4];
            sAt[(c0 * 4 + 0) * SA + rr] = v.x;
            sAt[(c0 * 4 + 1) * SA + rr] = v.y;
            sAt[(c0 * 4 + 2) * SA + rr] = v.z;
            sAt[(c0 * 4 + 3) * SA + rr] = v.w;
        }
    }
    if (FPOOL && tid < 64) sGb[tid] = (base + tid < n) ? batchv[base + tid] : -1;
    __syncthreads();

    const int w = tid >> 6, l = tid & 63;
    const int j = l & (QW - 1);
    const int rg = l >> LOGQ;                      // row group
    const int ob = w * (C_OUT / 4) + j * 4;        // first out column

    f32x4 acc[RPT];
    {
        const f32x4 bv = *(const f32x4*)&sB[ob];
        #pragma unroll
        for (int r = 0; r < RPT; ++r) acc[r] = bv;
    }

    #pragma unroll 4
    for (int k = 0; k < C_IN; ++k) {
        const f32x4 wv = ((const f32x4*)sW)[k * (C_OUT / 4) + (ob >> 2)];
        float av[RPT];
        if constexpr (RPT == 8) {
            const f32x4 a0 = *(const f32x4*)&sAt[k * SA + rg * 8];
            const f32x4 a1 = *(const f32x4*)&sAt[k * SA + rg * 8 + 4];
            av[0] = a0.x; av[1] = a0.y; av[2] = a0.z; av[3] = a0.w;
            av[4] = a1.x; av[5] = a1.y; av[6] = a1.z; av[7] = a1.w;
        } else if constexpr (RPT == 4) {
            const f32x4 a0 = *(const f32x4*)&sAt[k * SA + rg * 4];
            av[0] = a0.x; av[1] = a0.y; av[2] = a0.z; av[3] = a0.w;
        } else {
            const float2 a0 = *(const float2*)&sAt[k * SA + rg * 2];
            av[0] = a0.x; av[1] = a0.y;
        }
        #pragma unroll
        for (int r = 0; r < RPT; ++r) {
            acc[r].x = fmaf(av[r], wv.x, acc[r].x);
            acc[r].y = fmaf(av[r], wv.y, acc[r].y);
            acc[r].z = fmaf(av[r], wv.z, acc[r].z);
            acc[r].w = fmaf(av[r], wv.w, acc[r].w);
        }
    }

    if constexpr (!FPOOL) {
        #pragma unroll
        for (int r = 0; r < RPT; ++r) {
            const int node = base + rg * RPT + r;
            if (node < n) {
                f32x4 o;
                o.x = fmaxf(acc[r].x, 0.f); o.y = fmaxf(acc[r].y, 0.f);
                o.z = fmaxf(acc[r].z, 0.f); o.w = fmaxf(acc[r].w, 0.f);
                *(f32x4*)&h_out[(size_t)node * C_OUT + ob] = o;
            }
        }
    } else {
        __syncthreads();                           // k-loop reads of sW done (overlay!)
        #pragma unroll
        for (int r = 0; r < RPT; ++r) {
            const int row = rg * RPT + r;
            sP[row * SP + ob + 0] = fmaxf(acc[r].x, 0.f);
            sP[row * SP + ob + 1] = fmaxf(acc[r].y, 0.f);
            sP[row * SP + ob + 2] = fmaxf(acc[r].z, 0.f);
            sP[row * SP + ob + 3] = fmaxf(acc[r].w, 0.f);
        }
        __syncthreads();
        if (tid < 128) {                           // one thread per out column
            const int c = tid;
            int curg = -1; float run = 0.f;
            for (int r = 0; r < 64; ++r) {
                const int gb = sGb[r];
                if (gb < 0) continue;
                const float v = sP[r * SP + c];
                if (gb != curg) {
                    if (curg >= 0)
                        atomicMax((int*)&pooled[(size_t)curg * 128 + c], __float_as_int(run));
                    curg = gb; run = v;
                } else {
                    run = fmaxf(run, v);
                }
            }
            if (curg >= 0)
                atomicMax((int*)&pooled[(size_t)curg * 128 + c], __float_as_int(run));
        }
    }
}

// ---------------- MLP head: relu(pooled @ W5 + b5) @ W6 + b6 ----------------
__global__ void mlp_kernel(const float* __restrict__ pooled,
                           const float* __restrict__ W5, const float* __restrict__ b5,
                           const float* __restrict__ W6, const float* __restrict__ b6,
                           float* __restrict__ out) {
    const int g = blockIdx.x;
    const int t = threadIdx.x;  // 64 threads
    __shared__ float row[128];
    __shared__ float hid[64];
    row[t] = pooled[g * 128 + t];
    row[64 + t] = pooled[g * 128 + 64 + t];
    __syncthreads();
    float v = b5[t];
    #pragma unroll 8
    for (int c = 0; c < 128; ++c) v = fmaf(row[c], W5[c * 64 + t], v);
    hid[t] = fmaxf(v, 0.f);
    __syncthreads();
    if (t < 10) {
        float o = b6[t];
        #pragma unroll 8
        for (int c = 0; c < 64; ++c) o = fmaf(hid[c], W6[c * 10 + t], o);
        out[g * 10 + t] = o;
    }
}

extern "C" void kernel_launch(void* const* d_in, const int* in_sizes, int n_in,
                              void* d_out, int out_size, void* d_ws, size_t ws_size,
                              hipStream_t stream) {
    const float* x     = (const float*)d_in[0];
    const int*   ei    = (const int*)d_in[1];
    const int*   batch = (const int*)d_in[2];
    const float* W1 = (const float*)d_in[3];  const float* b1 = (const float*)d_in[4];
    const float* W2 = (const float*)d_in[5];  const float* b2 = (const float*)d_in[6];
    const float* W3 = (const float*)d_in[7];  const float* b3 = (const float*)d_in[8];
    const float* W4 = (const float*)d_in[9];  const float* b4 = (const float*)d_in[10];
    const float* W5 = (const float*)d_in[11]; const float* b5 = (const float*)d_in[12];
    const float* W6 = (const float*)d_in[13]; const float* b6 = (const float*)d_in[14];
    float* out = (float*)d_out;

    const int N = in_sizes[0] / 2;       // 100000
    const int E = in_sizes[1] / 2;       // 1600000
    const int G = out_size / 10;         // 512
    const int* src = ei;
    const int* dst = ei + E;

    // workspace layout (~85 MB)
    char* p = (char*)d_ws;
    auto take = [&](size_t bytes) -> void* {
        void* r = (void*)p;
        p += (bytes + 255) & ~(size_t)255;
        return r;
    };
    int*   cnt      = (int*)take((size_t)N * 4);
    int*   offs     = (int*)take((size_t)N * 4);
    int*   cursor   = (int*)take((size_t)N * 4);
    int*   bsums    = (int*)take(512 * 4);
    float* dis      = (float*)take((size_t)N * 4);
    int2*  meta     = (int2*)take((size_t)N * 8);
    int2*  csr_pk   = (int2*)take((size_t)E * 8);
    float* h1       = (float*)take((size_t)N * 16 * 4);
    float* h2       = (float*)take((size_t)N * 32 * 4);
    float* h3       = (float*)take((size_t)N * 64 * 4);
    float* aggb     = (float*)take((size_t)N * 64 * 4);   // shared agg buffer
    float* pooled   = (float*)take((size_t)G * 128 * 4);

    hipMemsetAsync(cnt, 0, (size_t)N * 4, stream);
    hipMemsetAsync(pooled, 0, (size_t)G * 128 * 4, stream);

    count_kernel<<<(E + 255) / 256, 256, 0, stream>>>(dst, cnt, E);

    const int NB = (N + 1023) / 1024;    // 98
    scan1_kernel<<<NB, 256, 0, stream>>>(cnt, offs, bsums, dis, N);
    scan2_kernel<<<1, 128, 0, stream>>>(bsums, NB);
    scan3_kernel<<<(N + 255) / 256, 256, 0, stream>>>(offs, bsums, cnt, cursor, meta, N);

    fill_kernel<<<(E + 255) / 256, 256, 0, stream>>>(src, dst, dis, cursor, csr_pk, E);

    gcn_l1<<<2048, 256, 0, stream>>>(x, meta, csr_pk, dis, W1, b1, h1, N, 2048 * 4);

    const int ABLK = (N + 3) / 4;        // 4 waves per 256-thr block, 1 node each
    const int GBLK = (N + 63) / 64;      // 64-node GEMM tiles

    agg_kernel<16><<<ABLK, 256, 0, stream>>>(h1, meta, csr_pk, dis, aggb, N);
    gemm_kernel<16, 32, false><<<GBLK, 256, 0, stream>>>(aggb, W2, b2, h2, nullptr, nullptr, N);

    agg_kernel<32><<<ABLK, 256, 0, stream>>>(h2, meta, csr_pk, dis, aggb, N);
    gemm_kernel<32, 64, false><<<GBLK, 256, 0, stream>>>(aggb, W3, b3, h3, nullptr, nullptr, N);

    agg_kernel<64><<<ABLK, 256, 0, stream>>>(h3, meta, csr_pk, dis, aggb, N);
    gemm_kernel<64, 128, true><<<GBLK, 256, 0, stream>>>(aggb, W4, b4, nullptr, batch, pooled, N);

    mlp_kernel<<<G, 64, 0, stream>>>(pooled, W5, b5, W6, b6, out);
}